// Round 9
// baseline (209.386 us; speedup 1.0000x reference)
//
#include <hip/hip_runtime.h>

#define D   256
#define BM  64      // rows per block (4 waves, 256 threads, 2 blocks/CU)
#define BN  128     // codes per group

typedef __attribute__((ext_vector_type(8))) short v8s;   // 8 bf16 = 4 VGPR
typedef __attribute__((ext_vector_type(4))) float v4f;
#define MFMA16 __builtin_amdgcn_mfma_f32_16x16x32_bf16

// counted vmcnt wait; "memory" clobber pins VMEM issue order around it.
#define WAITVM(N) asm volatile("s_waitcnt vmcnt(" #N ")" ::: "memory")
// DS-pinning scheduler fence (runtime-free). Raw s_barrier is NOT a compiler
// memory fence — without a fence, LLVM may hoist a ds_read of the freshly-
// staged buffer above the barrier into the WAITVM..barrier gap, reading
// another wave's staging region before that wave's WAITVM certified its DMA
// landed (the r5 race). Mask 0x7F allows ALU/VALU/SALU/MFMA/VMEM to cross
// (register-only or provably-safe motion; VMEM is additionally pinned at
// WAITVM by its IR memory clobber) while DS ops (0x80|0x100|0x200) are
// pinned — blocking exactly the racy motion and nothing else. r8 measured
// mask-0 fences at ~23 us on this schedule (120.8 -> 143.9).
#define DSFENCE() __builtin_amdgcn_sched_barrier(0x7F)

static __device__ inline unsigned short f2bf(float f) {          // RNE
    unsigned u = __float_as_uint(f);
    return (unsigned short)((u + 0x7fffu + ((u >> 16) & 1u)) >> 16);
}
static __device__ inline float bf2f(unsigned short s) {
    return __uint_as_float(((unsigned)s) << 16);
}

// async global->LDS, 16 B per lane. LDS dest must be wave-uniform (HW adds lane*16).
static __device__ inline void gl_lds16(const unsigned short* g, unsigned short* l) {
    __builtin_amdgcn_global_load_lds(
        (const __attribute__((address_space(1))) unsigned int*)g,
        (__attribute__((address_space(3))) unsigned int*)l, 16, 0, 0);
}

// ---------------- kernel 1a: exact c2 (+ zero the loss accumulator) ----------------
__global__ void vq_prep_c2(const float* __restrict__ cb, float* __restrict__ c2,
                           float* __restrict__ loss) {
    const int row  = blockIdx.x;
    const int lane = threadIdx.x;  // 64
    if (row == 0 && lane == 0) loss[0] = 0.0f;
    const float4 v = *reinterpret_cast<const float4*>(cb + (size_t)row * D + lane * 4);
    float s = v.x * v.x + v.y * v.y + v.z * v.z + v.w * v.w;
    #pragma unroll
    for (int off = 32; off > 0; off >>= 1) s += __shfl_down(s, off, 64);
    if (lane == 0) c2[row] = s;
}

// ---------------- kernel 1b: codebook -> bf16 hi/lo, chunk-major pre-swizzled ----------------
// Chunk (nc_i, kc_i) = 128 codes x 64 k = 1024 granules of 16 B (8 bf16).
// Granule p within chunk: seg = p>>7 (k-octet 0..7), n = (p&127) ^ seg.
// Lane-linear DMA reproduces this in LDS: MFMA read octets (col 0..7, seg const)
// hit bank-groups (col^seg)&7, all distinct -> conflict-free.
__global__ void vq_prep_sw(const float* __restrict__ cb,
                           unsigned short* __restrict__ cbh, unsigned short* __restrict__ cbl) {
    const int b     = blockIdx.x;          // 256 blocks, 4 per chunk
    const int chunk = b >> 2;
    const int nc = (chunk >> 2) * BN;
    const int kc = (chunk & 3) * 64;
    const int p   = (b & 3) * 256 + threadIdx.x;
    const int seg = p >> 7;
    const int n   = (p & 127) ^ seg;
    const float* src = cb + (size_t)(nc + n) * D + kc + seg * 8;
    const float4 f0 = *reinterpret_cast<const float4*>(src);
    const float4 f1 = *reinterpret_cast<const float4*>(src + 4);
    const float f[8] = {f0.x, f0.y, f0.z, f0.w, f1.x, f1.y, f1.z, f1.w};
    v8s h, l;
    #pragma unroll
    for (int j = 0; j < 8; ++j) {
        unsigned short hb = f2bf(f[j]);
        h[j] = (short)hb;
        l[j] = (short)f2bf(f[j] - bf2f(hb));
    }
    const size_t o = ((size_t)chunk * 1024 + p) * 8;
    *reinterpret_cast<v8s*>(cbh + o) = h;
    *reinterpret_cast<v8s*>(cbl + o) = l;
}

// ---------------- kernel 2: MFMA argmin + fused gather/loss ----------------
// r1 two-phase counted-vmcnt schedule with minimal DS-only fences:
//   phase A: WAITVM(4) [s.h landed] ; s_barrier ; DSFENCE ; issue (s+1).h ;
//            8 ds_read + 32 MFMA
//   phase B: WAITVM(4) [s.l landed] ; s_barrier ; DSFENCE ; issue (s+1).l ;
//            8 ds_read + 16 MFMA
// Per-wave VMEM order: ... s.h(4), s.l(4), (s+1).h(4), (s+1).l(4) ... so at each
// phase entry the needed 4 loads are the oldest of 8 outstanding; WAITVM(4)
// retires exactly them and the DMA queue never drains in the main loop.
__global__ __launch_bounds__(256, 2) void vq_argmin_mfma(
        const float* __restrict__ x, const float* __restrict__ cb,
        const unsigned short* __restrict__ cbh, const unsigned short* __restrict__ cbl,
        const float* __restrict__ c2, float* __restrict__ idx_out,
        float* __restrict__ qout, float* __restrict__ loss, float scale, int N) {
    __shared__ unsigned short lds_h[2][8192];   // 2 x 16 KB (double-buffered h-chunks)
    __shared__ unsigned short lds_l[2][8192];   // 2 x 16 KB
    __shared__ float c2s[2048];                 // 8 KB  -> 72 KB, 2 blocks/CU

    const int tid  = threadIdx.x;
    const int w    = tid >> 6;      // 4 waves
    const int lane = tid & 63;
    const int col  = lane & 15;     // MFMA col / A-row selector
    const int quad = lane >> 4;     // k-octet selector
    const int mg   = w >> 1;        // 0..1 : 32-row slice
    const int ng   = w & 1;         // 0..1 : 64-code half of the group
    const int m0   = blockIdx.x * BM;
    const int n_groups = N >> 7;
    const int n_stages = n_groups * 4;

    // per-wave staging: wave w stages granules [w*256, w*256+256) of each chunk
    const unsigned short* gh0 = cbh + ((size_t)(w * 256 + lane)) * 8;
    const unsigned short* gl0 = cbl + ((size_t)(w * 256 + lane)) * 8;

    // prologue: issue stage 0 (8 DMAs); they fly during setup below
    #pragma unroll
    for (int i = 0; i < 4; ++i) {
        gl_lds16(gh0 + i * 512, &lds_h[0][(w * 256 + i * 64) * 8]);
        gl_lds16(gl0 + i * 512, &lds_l[0][(w * 256 + i * 64) * 8]);
    }

    // ---- c2 -> LDS ----
    {
        const int o = tid * 8;
        if (o < N) {
            const float4 a = *reinterpret_cast<const float4*>(c2 + o);
            const float4 b = *reinterpret_cast<const float4*>(c2 + o + 4);
            *reinterpret_cast<float4*>(&c2s[o])     = a;
            *reinterpret_cast<float4*>(&c2s[o + 4]) = b;
        }
    }

    // ---- A-frags: rows m0 + mg*32 + mt*16 + col, full K, hi+lo (128 VGPR) ----
    v8s xh[2][8], xl[2][8];
    #pragma unroll
    for (int mt = 0; mt < 2; ++mt) {
        const float* xr = x + (size_t)(m0 + mg * 32 + mt * 16 + col) * D;
        #pragma unroll
        for (int ks = 0; ks < 8; ++ks) {
            const int kb = ks * 32 + quad * 8;
            const float4 f0 = *reinterpret_cast<const float4*>(xr + kb);
            const float4 f1 = *reinterpret_cast<const float4*>(xr + kb + 4);
            float f[8] = {f0.x, f0.y, f0.z, f0.w, f1.x, f1.y, f1.z, f1.w};
            v8s h, l;
            #pragma unroll
            for (int j = 0; j < 8; ++j) {
                unsigned short hb = f2bf(f[j]);
                h[j] = (short)hb;
                l[j] = (short)f2bf(f[j] - bf2f(hb));
            }
            xh[mt][ks] = h; xl[mt][ks] = l;
        }
    }

    float runmin[2][4];
    int   runidx[2][4];
    #pragma unroll
    for (int mt = 0; mt < 2; ++mt)
        #pragma unroll
        for (int r = 0; r < 4; ++r) { runmin[mt][r] = 3.4e38f; runidx[mt][r] = 0; }

    v4f acc[4][2];
    #pragma unroll
    for (int nt = 0; nt < 4; ++nt)
        #pragma unroll
        for (int mt = 0; mt < 2; ++mt) acc[nt][mt] = 0.0f;

    __syncthreads();   // publish c2s (prologue-once full drain; stage 0 landed)

    for (int g = 0; g < n_groups; ++g) {
        #pragma unroll
        for (int cc = 0; cc < 4; ++cc) {           // compile-time chunk index
            const int par   = cc & 1;              // static buffer parity
            const int stage = g * 4 + cc;
            const bool more = (stage + 1 < n_stages);

            // ================= phase A: hi-half =================
            WAITVM(4);                              // s.h landed (s.l may fly)
            __builtin_amdgcn_s_barrier();           // all waves' s.h published
            DSFENCE();
            if (more) {
                const unsigned short* gh = gh0 + (size_t)(stage + 1) * 8192;
                unsigned short* lh = &lds_h[par ^ 1][0];
                #pragma unroll
                for (int i = 0; i < 4; ++i)
                    gl_lds16(gh + i * 512, lh + (w * 256 + i * 64) * 8);
            }
            __builtin_amdgcn_s_setprio(1);
            #pragma unroll
            for (int ksk = 0; ksk < 2; ++ksk) {
                const int ks  = cc * 2 + ksk;       // static 0..7
                const int seg = ksk * 4 + quad;     // 0..7
                #pragma unroll
                for (int nt = 0; nt < 4; ++nt) {
                    const int p = seg * BN + ((ng * 64 + nt * 16 + col) ^ seg);
                    const v8s ch = *reinterpret_cast<const v8s*>(&lds_h[par][p * 8]);
                    #pragma unroll
                    for (int mt = 0; mt < 2; ++mt) {
                        acc[nt][mt] = MFMA16(xh[mt][ks], ch, acc[nt][mt], 0, 0, 0);
                        acc[nt][mt] = MFMA16(xl[mt][ks], ch, acc[nt][mt], 0, 0, 0);
                    }
                }
            }
            __builtin_amdgcn_s_setprio(0);

            // ================= phase B: lo-half =================
            if (more) { WAITVM(4); }                // s.l landed ((s+1).h may fly)
            else      { WAITVM(0); }                // last stage: drain
            __builtin_amdgcn_s_barrier();
            DSFENCE();
            if (more) {
                const unsigned short* gl = gl0 + (size_t)(stage + 1) * 8192;
                unsigned short* ll = &lds_l[par ^ 1][0];
                #pragma unroll
                for (int i = 0; i < 4; ++i)
                    gl_lds16(gl + i * 512, ll + (w * 256 + i * 64) * 8);
            }
            __builtin_amdgcn_s_setprio(1);
            #pragma unroll
            for (int ksk = 0; ksk < 2; ++ksk) {
                const int ks  = cc * 2 + ksk;
                const int seg = ksk * 4 + quad;
                #pragma unroll
                for (int nt = 0; nt < 4; ++nt) {
                    const int p = seg * BN + ((ng * 64 + nt * 16 + col) ^ seg);
                    const v8s cl = *reinterpret_cast<const v8s*>(&lds_l[par][p * 8]);
                    #pragma unroll
                    for (int mt = 0; mt < 2; ++mt)
                        acc[nt][mt] = MFMA16(xh[mt][ks], cl, acc[nt][mt], 0, 0, 0);
                }
            }
            __builtin_amdgcn_s_setprio(0);
        }

        // finalize this n-group (registers + read-only c2s — no barrier needed)
        #pragma unroll
        for (int nt = 0; nt < 4; ++nt) {
            const int n = g * BN + ng * 64 + nt * 16 + col;
            const float c2n = c2s[n];
            #pragma unroll
            for (int mt = 0; mt < 2; ++mt) {
                #pragma unroll
                for (int r = 0; r < 4; ++r) {
                    const float s = c2n - 2.0f * acc[nt][mt][r];
                    if (s < runmin[mt][r]) { runmin[mt][r] = s; runidx[mt][r] = n; }
                }
                acc[nt][mt] = 0.0f;
            }
        }
    }

    // ---- merge: row = mg*32 + mt*16 + quad*4 + r ; slot = (ng*16+col) ^ (row&31) ----
    __syncthreads();
    float* red_v = reinterpret_cast<float*>(&lds_h[0][0]);   // [64][32] f32, 8 KB
    int*   red_i = reinterpret_cast<int*>(&lds_l[0][0]);     // [64][32] i32, 8 KB
    #pragma unroll
    for (int mt = 0; mt < 2; ++mt)
        #pragma unroll
        for (int r = 0; r < 4; ++r) {
            const int row  = mg * 32 + mt * 16 + quad * 4 + r;
            const int slot = (ng * 16 + col) ^ (row & 31);
            red_v[row * 32 + slot] = runmin[mt][r];
            red_i[row * 32 + slot] = runidx[mt][r];
        }
    __syncthreads();
    float best = 3.4e38f;
    int   bidx = 0;
    if (tid < 64) {
        #pragma unroll 4
        for (int t = 0; t < 32; ++t) {
            const int  sl = t ^ (tid & 31);
            const float v = red_v[tid * 32 + sl];
            const int  id = red_i[tid * 32 + sl];
            if (v < best || (v == best && id < bidx)) { best = v; bidx = id; }
        }
        idx_out[m0 + tid] = (float)bidx;
    }
    __syncthreads();
    int* idx_sh = reinterpret_cast<int*>(&lds_h[1][0]);
    if (tid < 64) idx_sh[tid] = bidx;
    __syncthreads();

    // ---- fused gather + loss over this block's 64 rows (x tile is L2-hot) ----
    const float* xg2 = x + (size_t)m0 * D;
    float s = 0.0f;
    #pragma unroll
    for (int i = 0; i < 16; ++i) {
        const int gix = i * 256 + tid;      // float4-granule, 4096 total
        const int row = gix >> 6;
        const int k4  = (gix & 63) * 4;
        const int idx = idx_sh[row];
        const float4 c  = *reinterpret_cast<const float4*>(cb  + (size_t)idx * D + k4);
        const float4 xv = *reinterpret_cast<const float4*>(xg2 + (size_t)row * D + k4);
        *reinterpret_cast<float4*>(qout + (size_t)(m0 + row) * D + k4) = c;
        const float dx = c.x - xv.x, dy = c.y - xv.y, dz = c.z - xv.z, dw = c.w - xv.w;
        s += dx * dx + dy * dy + dz * dz + dw * dw;
    }
    #pragma unroll
    for (int off = 32; off > 0; off >>= 1) s += __shfl_down(s, off, 64);
    float* wsum = reinterpret_cast<float*>(&lds_l[1][0]);
    if ((tid & 63) == 0) wsum[tid >> 6] = s;
    __syncthreads();
    if (tid == 0) {
        atomicAdd(loss, (wsum[0] + wsum[1] + wsum[2] + wsum[3]) * scale);
    }
}

extern "C" void kernel_launch(void* const* d_in, const int* in_sizes, int n_in,
                              void* d_out, int out_size, void* d_ws, size_t ws_size,
                              hipStream_t stream) {
    const float* x  = (const float*)d_in[0];
    const float* cb = (const float*)d_in[1];
    const int M = in_sizes[0] / D;   // 32768
    const int N = in_sizes[1] / D;   // 2048

    float* qout    = (float*)d_out;
    float* idx_out = qout + (size_t)M * D;
    float* loss    = idx_out + M;

    // ws layout (bytes): c2 [0,8K) | cbh_sw [8K, +1M) | cbl_sw [+1M)
    char* wsb = (char*)d_ws;
    float*          c2  = (float*)wsb;
    unsigned short* cbh = (unsigned short*)(wsb + 8192);
    unsigned short* cbl = cbh + (size_t)N * D;

    vq_prep_c2<<<N, 64, 0, stream>>>(cb, c2, loss);
    vq_prep_sw<<<(N / BN) * 4 * 4, 256, 0, stream>>>(cb, cbh, cbl);
    const float scale = 2.0f / (float)((size_t)M * D);
    vq_argmin_mfma<<<M / BM, 256, 0, stream>>>(x, cb, cbh, cbl, c2, idx_out, qout,
                                               loss, scale, N);
}

// Round 10
// 181.634 us; speedup vs baseline: 1.1528x; 1.1528x over previous
//
#include <hip/hip_runtime.h>

#define D   256
#define BM  64      // rows per block (4 waves, 256 threads)
#define BN  128     // codes per group

typedef __attribute__((ext_vector_type(8))) short v8s;   // 8 bf16 = 4 VGPR
typedef __attribute__((ext_vector_type(4))) float v4f;
#define MFMA16 __builtin_amdgcn_mfma_f32_16x16x32_bf16
// pin: B-loads issued above this point may not be crossed by the MFMAs below
#define SB0() __builtin_amdgcn_sched_barrier(0)

static __device__ inline unsigned short f2bf(float f) {          // RNE
    unsigned u = __float_as_uint(f);
    return (unsigned short)((u + 0x7fffu + ((u >> 16) & 1u)) >> 16);
}
static __device__ inline float bf2f(unsigned short s) {
    return __uint_as_float(((unsigned)s) << 16);
}

// ---------------- kernel 1a: exact c2 (+ zero the loss accumulator) ----------------
__global__ void vq_prep_c2(const float* __restrict__ cb, float* __restrict__ c2,
                           float* __restrict__ loss) {
    const int row  = blockIdx.x;
    const int lane = threadIdx.x;  // 64
    if (row == 0 && lane == 0) loss[0] = 0.0f;
    const float4 v = *reinterpret_cast<const float4*>(cb + (size_t)row * D + lane * 4);
    float s = v.x * v.x + v.y * v.y + v.z * v.z + v.w * v.w;
    #pragma unroll
    for (int off = 32; off > 0; off >>= 1) s += __shfl_down(s, off, 64);
    if (lane == 0) c2[row] = s;
}

// ---------------- kernel 1b: codebook -> bf16 hi/lo, FRAGMENT-major ----------------
// Storage position p (0..65535), 16 B granule each, per dtype:
//   col=p&15, q=(p>>4)&3, f=(p>>6)&7, ng=(p>>9)&1, s=p>>10 (stage 0..63)
//   g=s>>2, cc=s&3, nt=f&3, ksk=f>>2, seg=ksk*4+q
//   code n = g*128 + ng*64 + nt*16 + col ; k0 = cc*64 + seg*8 (8 bf16)
// A wave's B-fragment (stage s, ng, dtype, f) is 64 consecutive granules:
// lane l reads byte l*16 — perfectly coalesced 1 KB global_load_dwordx4.
__global__ void vq_prep_frag(const float* __restrict__ cb,
                             unsigned short* __restrict__ cbh,
                             unsigned short* __restrict__ cbl) {
    const int p   = blockIdx.x * 256 + threadIdx.x;   // grid 256 -> 65536
    const int col = p & 15;
    const int q   = (p >> 4) & 3;
    const int f   = (p >> 6) & 7;
    const int ng  = (p >> 9) & 1;
    const int s   = p >> 10;
    const int g = s >> 2, cc = s & 3;
    const int nt = f & 3, ksk = f >> 2;
    const int seg = ksk * 4 + q;
    const int n  = g * 128 + ng * 64 + nt * 16 + col;
    const int k0 = cc * 64 + seg * 8;
    const float* src = cb + (size_t)n * D + k0;
    const float4 f0 = *reinterpret_cast<const float4*>(src);
    const float4 f1 = *reinterpret_cast<const float4*>(src + 4);
    const float fv[8] = {f0.x, f0.y, f0.z, f0.w, f1.x, f1.y, f1.z, f1.w};
    v8s h, l;
    #pragma unroll
    for (int j = 0; j < 8; ++j) {
        unsigned short hb = f2bf(fv[j]);
        h[j] = (short)hb;
        l[j] = (short)f2bf(fv[j] - bf2f(hb));
    }
    *reinterpret_cast<v8s*>(cbh + (size_t)p * 8) = h;
    *reinterpret_cast<v8s*>(cbl + (size_t)p * 8) = l;
}

// ---------------- kernel 2: barrier-free MFMA argmin + fused gather/loss ----------------
// B-fragments load global->register (double-buffered banks), no LDS staging, no
// barriers, no inline waitcnt: waves are fully independent in the main loop and
// the compiler's per-register vmcnt tracking provides exact waits. Per chunk:
// issue next chunk's 16 coalesced 1 KB loads, then 48 MFMAs on the landed bank
// (~770 cyc — covers L2 latency with depth-1 prefetch; 16 KB/wave in flight).
// Race-free by construction (no shared mutable state until the epilogue).
__global__ __launch_bounds__(256, 1) void vq_argmin_mfma(
        const float* __restrict__ x, const float* __restrict__ cb,
        const unsigned short* __restrict__ cbh, const unsigned short* __restrict__ cbl,
        const float* __restrict__ c2, float* __restrict__ idx_out,
        float* __restrict__ qout, float* __restrict__ loss, float scale, int N) {
    __shared__ float red_v[64 * 32];   // 8 KB
    __shared__ int   red_i[64 * 32];   // 8 KB
    __shared__ float c2s[2048];        // 8 KB
    __shared__ int   idx_sh[64];
    __shared__ float wsum[4];

    const int tid  = threadIdx.x;
    const int w    = tid >> 6;      // 4 waves
    const int lane = tid & 63;
    const int col  = lane & 15;     // MFMA col / A-row selector
    const int quad = lane >> 4;     // k-octet selector
    const int mg   = w >> 1;        // 0..1 : 32-row slice
    const int ng   = w & 1;         // 0..1 : 64-code half of the group
    const int m0   = blockIdx.x * BM;
    const int n_groups = N >> 7;

    // per-lane fragment base: stage s block = s*16384 B; ng sub-block 8192 B;
    // fragment f at +f*1024; lane at +lane*16.
    const char* bh = (const char*)cbh + (size_t)ng * 8192 + (size_t)lane * 16;
    const char* bl = (const char*)cbl + (size_t)ng * 8192 + (size_t)lane * 16;

#define LOADB(CH, CL, S)                                                       \
    {                                                                          \
        const char* ph = bh + (size_t)(S) * 16384;                             \
        const char* pl = bl + (size_t)(S) * 16384;                             \
        _Pragma("unroll")                                                      \
        for (int f = 0; f < 8; ++f) {                                          \
            CH[f] = *reinterpret_cast<const v8s*>(ph + f * 1024);              \
            CL[f] = *reinterpret_cast<const v8s*>(pl + f * 1024);              \
        }                                                                      \
    }

    // B register banks (ping-pong by chunk parity)
    v8s chA[8], clA[8], chB[8], clB[8];
    LOADB(chA, clA, 0);                 // stage-0 loads fly during setup below

    // ---- c2 -> LDS ----
    {
        const int o = tid * 8;
        if (o < N) {
            const float4 a = *reinterpret_cast<const float4*>(c2 + o);
            const float4 b = *reinterpret_cast<const float4*>(c2 + o + 4);
            *reinterpret_cast<float4*>(&c2s[o])     = a;
            *reinterpret_cast<float4*>(&c2s[o + 4]) = b;
        }
    }

    // ---- A-frags: rows m0 + mg*32 + mt*16 + col, full K, hi+lo (128 VGPR) ----
    v8s xh[2][8], xl[2][8];
    #pragma unroll
    for (int mt = 0; mt < 2; ++mt) {
        const float* xr = x + (size_t)(m0 + mg * 32 + mt * 16 + col) * D;
        #pragma unroll
        for (int ks = 0; ks < 8; ++ks) {
            const int kb = ks * 32 + quad * 8;
            const float4 f0 = *reinterpret_cast<const float4*>(xr + kb);
            const float4 f1 = *reinterpret_cast<const float4*>(xr + kb + 4);
            float fv[8] = {f0.x, f0.y, f0.z, f0.w, f1.x, f1.y, f1.z, f1.w};
            v8s h, l;
            #pragma unroll
            for (int j = 0; j < 8; ++j) {
                unsigned short hb = f2bf(fv[j]);
                h[j] = (short)hb;
                l[j] = (short)f2bf(fv[j] - bf2f(hb));
            }
            xh[mt][ks] = h; xl[mt][ks] = l;
        }
    }

    float runmin[2][4];
    int   runidx[2][4];
    #pragma unroll
    for (int mt = 0; mt < 2; ++mt)
        #pragma unroll
        for (int r = 0; r < 4; ++r) { runmin[mt][r] = 3.4e38f; runidx[mt][r] = 0; }

    v4f acc[4][2];
    #pragma unroll
    for (int nt = 0; nt < 4; ++nt)
        #pragma unroll
        for (int mt = 0; mt < 2; ++mt) acc[nt][mt] = 0.0f;

    __syncthreads();   // publish c2s (one-time)

#define COMP(CH, CL, CC)                                                       \
    _Pragma("unroll")                                                          \
    for (int ksk = 0; ksk < 2; ++ksk) {                                        \
        const int ks = (CC) * 2 + ksk;                                         \
        _Pragma("unroll")                                                      \
        for (int nt = 0; nt < 4; ++nt) {                                       \
            const v8s ch = CH[ksk * 4 + nt];                                   \
            const v8s cl = CL[ksk * 4 + nt];                                   \
            _Pragma("unroll")                                                  \
            for (int mt = 0; mt < 2; ++mt) {                                   \
                acc[nt][mt] = MFMA16(xh[mt][ks], ch, acc[nt][mt], 0, 0, 0);    \
                acc[nt][mt] = MFMA16(xl[mt][ks], ch, acc[nt][mt], 0, 0, 0);    \
                acc[nt][mt] = MFMA16(xh[mt][ks], cl, acc[nt][mt], 0, 0, 0);    \
            }                                                                  \
        }                                                                      \
    }

    for (int g = 0; g < n_groups; ++g) {
        const int s0 = g * 4;
        // chunk 0: compute A-bank, prefetch stage s0+1 into B-bank
        LOADB(chB, clB, s0 + 1); SB0();
        COMP(chA, clA, 0);
        // chunk 1: compute B, prefetch s0+2 into A
        LOADB(chA, clA, s0 + 2); SB0();
        COMP(chB, clB, 1);
        // chunk 2: compute A, prefetch s0+3 into B
        LOADB(chB, clB, s0 + 3); SB0();
        COMP(chA, clA, 2);
        // chunk 3: compute B, prefetch s0+4 into A
        // (g==15 reads the 16 KB pad after cbl — in-bounds, never consumed)
        LOADB(chA, clA, s0 + 4); SB0();
        COMP(chB, clB, 3);

        // finalize this n-group (registers + read-only c2s)
        #pragma unroll
        for (int nt = 0; nt < 4; ++nt) {
            const int n = g * BN + ng * 64 + nt * 16 + col;
            const float c2n = c2s[n];
            #pragma unroll
            for (int mt = 0; mt < 2; ++mt) {
                #pragma unroll
                for (int r = 0; r < 4; ++r) {
                    const float s = c2n - 2.0f * acc[nt][mt][r];
                    if (s < runmin[mt][r]) { runmin[mt][r] = s; runidx[mt][r] = n; }
                }
                acc[nt][mt] = 0.0f;
            }
        }
    }
#undef LOADB
#undef COMP

    // ---- merge: row = mg*32 + mt*16 + quad*4 + r ; slot = (ng*16+col) ^ (row&31) ----
    __syncthreads();
    #pragma unroll
    for (int mt = 0; mt < 2; ++mt)
        #pragma unroll
        for (int r = 0; r < 4; ++r) {
            const int row  = mg * 32 + mt * 16 + quad * 4 + r;
            const int slot = (ng * 16 + col) ^ (row & 31);
            red_v[row * 32 + slot] = runmin[mt][r];
            red_i[row * 32 + slot] = runidx[mt][r];
        }
    __syncthreads();
    float best = 3.4e38f;
    int   bidx = 0;
    if (tid < 64) {
        #pragma unroll 4
        for (int t = 0; t < 32; ++t) {
            const int  sl = t ^ (tid & 31);
            const float v = red_v[tid * 32 + sl];
            const int  id = red_i[tid * 32 + sl];
            if (v < best || (v == best && id < bidx)) { best = v; bidx = id; }
        }
        idx_out[m0 + tid] = (float)bidx;
        idx_sh[tid] = bidx;
    }
    __syncthreads();

    // ---- fused gather + loss over this block's 64 rows (x tile is L2-hot) ----
    const float* xg2 = x + (size_t)m0 * D;
    float s = 0.0f;
    #pragma unroll
    for (int i = 0; i < 16; ++i) {
        const int gix = i * 256 + tid;      // float4-granule, 4096 total
        const int row = gix >> 6;
        const int k4  = (gix & 63) * 4;
        const int idx = idx_sh[row];
        const float4 c  = *reinterpret_cast<const float4*>(cb  + (size_t)idx * D + k4);
        const float4 xv = *reinterpret_cast<const float4*>(xg2 + (size_t)row * D + k4);
        *reinterpret_cast<float4*>(qout + (size_t)(m0 + row) * D + k4) = c;
        const float dx = c.x - xv.x, dy = c.y - xv.y, dz = c.z - xv.z, dw = c.w - xv.w;
        s += dx * dx + dy * dy + dz * dz + dw * dw;
    }
    #pragma unroll
    for (int off = 32; off > 0; off >>= 1) s += __shfl_down(s, off, 64);
    if ((tid & 63) == 0) wsum[tid >> 6] = s;
    __syncthreads();
    if (tid == 0) {
        atomicAdd(loss, (wsum[0] + wsum[1] + wsum[2] + wsum[3]) * scale);
    }
}

extern "C" void kernel_launch(void* const* d_in, const int* in_sizes, int n_in,
                              void* d_out, int out_size, void* d_ws, size_t ws_size,
                              hipStream_t stream) {
    const float* x  = (const float*)d_in[0];
    const float* cb = (const float*)d_in[1];
    const int M = in_sizes[0] / D;   // 32768
    const int N = in_sizes[1] / D;   // 2048

    float* qout    = (float*)d_out;
    float* idx_out = qout + (size_t)M * D;
    float* loss    = idx_out + M;

    // ws layout (bytes): c2 [0,8K) | cbh [8K,+1M) | cbl [+1M) | pad 16K
    // (pad absorbs the branchless last-iteration overshoot prefetch)
    char* wsb = (char*)d_ws;
    float*          c2  = (float*)wsb;
    unsigned short* cbh = (unsigned short*)(wsb + 8192);
    unsigned short* cbl = cbh + (size_t)N * D;

    vq_prep_c2<<<N, 64, 0, stream>>>(cb, c2, loss);
    vq_prep_frag<<<(N * D * 2 / 16) / 256, 256, 0, stream>>>(cb, cbh, cbl);
    const float scale = 2.0f / (float)((size_t)M * D);
    vq_argmin_mfma<<<M / BM, 256, 0, stream>>>(x, cb, cbh, cbl, c2, idx_out, qout,
                                               loss, scale, N);
}